// Round 3
// baseline (552.010 us; speedup 1.0000x reference)
//
#include <hip/hip_runtime.h>
#include <hip/hip_bf16.h>

typedef __bf16 bf16_t;
typedef __bf16 bf16x8 __attribute__((ext_vector_type(8)));
typedef float f32x4 __attribute__((ext_vector_type(4)));

#define AS1 __attribute__((address_space(1)))
#define AS3 __attribute__((address_space(3)))

__device__ __forceinline__ void gload_lds16(const void* g, void* l) {
    __builtin_amdgcn_global_load_lds((const AS1 void*)g, (AS3 void*)l, 16, 0, 0);
}

__device__ __forceinline__ float gelu_f(float x) {
    // jax.nn.gelu default: tanh approximation
    float u = 0.7978845608028654f * (x + 0.044715f * x * x * x);
    float e = __expf(2.0f * u);
    float t = 1.0f - 2.0f / (e + 1.0f);   // tanh(u), safe at +-inf
    return 0.5f * x * (1.0f + t);
}

// ---------------------------------------------------------------------------
// Dtype detect (validated R4): low-16 exponent-field concentration test.
// flag: 1 = bf16-packed inputs, 0 = f32 inputs. (R4 evidence: f32.)
// ---------------------------------------------------------------------------
__global__ void detect_kernel(const unsigned int* __restrict__ xw,
                              int* __restrict__ flagp)
{
    __shared__ int cnt;
    int tid = threadIdx.x;
    if (tid == 0) cnt = 0;
    __syncthreads();
    unsigned int w = xw[tid];
    int le = (w >> 7) & 0xFF;
    int ok = (le >= 0x60 && le <= 0x88) ? 1 : 0;
    atomicAdd(&cnt, ok);
    __syncthreads();
    if (tid == 0) *flagp = (cnt >= 128) ? 1 : 0;
}

__device__ __forceinline__ float rd_elem(const void* p, size_t idx, int isbf) {
    return isbf ? (float)((const bf16_t*)p)[idx] : ((const float*)p)[idx];
}

// ---------------------------------------------------------------------------
// Convert x -> bf16 xb [32768*512]. One 8-elem chunk per thread.
// ---------------------------------------------------------------------------
__global__ __launch_bounds__(256) void convert_kernel(
    const void* __restrict__ x, const int* __restrict__ flagp,
    bf16_t* __restrict__ xb)
{
    const int isbf = *flagp;
    size_t i = (size_t)blockIdx.x * 256 + threadIdx.x;   // chunk id, 2097152 total
    if (isbf) {
        ((bf16x8*)xb)[i] = ((const bf16x8*)x)[i];
    } else {
        const float* s = (const float*)x + i * 8;
        float4 u0 = *(const float4*)s;
        float4 u1 = *(const float4*)(s + 4);
        bf16x8 v;
        v[0] = (bf16_t)u0.x; v[1] = (bf16_t)u0.y;
        v[2] = (bf16_t)u0.z; v[3] = (bf16_t)u0.w;
        v[4] = (bf16_t)u1.x; v[5] = (bf16_t)u1.y;
        v[6] = (bf16_t)u1.z; v[7] = (bf16_t)u1.w;
        ((bf16x8*)xb)[i] = v;
    }
}

// ---------------------------------------------------------------------------
// Weight pack -> bf16 B^T ([N,K] row-major) copies in workspace.
//  W1t [2048][512], W2t [512][2048], Wat [1024][512], Wbt [512][1024].
// ---------------------------------------------------------------------------
__global__ __launch_bounds__(256) void pack_kernel(
    const void* __restrict__ W1, const void* __restrict__ W2,
    const void* __restrict__ Wa1, const void* __restrict__ Wa2,
    const void* __restrict__ Wb1, const void* __restrict__ Wb2,
    const int* __restrict__ flagp,
    bf16_t* __restrict__ W1t, bf16_t* __restrict__ W2t,
    bf16_t* __restrict__ Wat, bf16_t* __restrict__ Wbt)
{
    const int isbf = *flagp;
    int i = blockIdx.x * 256 + threadIdx.x;
    if (i < 1048576) {                       // W1t[n][k] = W1[k][n], [512,2048]
        int n = i >> 9, k = i & 511;
        W1t[i] = (bf16_t)rd_elem(W1, (size_t)k * 2048 + n, isbf);
    } else if (i < 2097152) {                // W2t[n][k] = W2[k][n], [2048,512]
        int j = i - 1048576;
        int n = j >> 11, k = j & 2047;
        W2t[j] = (bf16_t)rd_elem(W2, (size_t)k * 512 + n, isbf);
    } else if (i < 2621440) {                // Wat[n][d] = Wa_g[e][d][h]
        int j = i - 2097152;
        int n = j >> 9, d = j & 511;
        const void* Wa = (n < 512) ? Wa1 : Wa2;
        int nn = n & 511, e = nn >> 6, hh = nn & 63;
        Wat[j] = (bf16_t)rd_elem(Wa, ((size_t)e * 512 + d) * 64 + hh, isbf);
    } else {                                 // Wbt[dout][k] = Wb_g[e][h][dout]
        int j = i - 2621440;
        int d = j >> 10, n = j & 1023;
        const void* Wb = (n < 512) ? Wb1 : Wb2;
        int nn = n & 511;
        Wbt[j] = (bf16_t)rd_elem(Wb, (size_t)nn * 512 + d, isbf);
    }
}

// ---------------------------------------------------------------------------
// Gate: masked token r in [0,16384), token = (r>>12)*8192 + 4096 + (r&4095).
// CRITICAL (R5/R6 post-mortem): logits MUST be computed from x at source
// precision (f32 path), NOT from bf16 xb — top-2 selection is discontinuous;
// bf16-rounded logits flip near-tied expert choices vs the reference.
// ---------------------------------------------------------------------------
__global__ __launch_bounds__(256) void gate_kernel(
    const void* __restrict__ xv,
    const void* __restrict__ Wg1, const void* __restrict__ Wg2,
    const int* __restrict__ flagp,
    float* __restrict__ wout)
{
    __shared__ float WgL[2][4096];   // [512][8] each, f32
    const int isbf = *flagp;
    const int tid = threadIdx.x;
    const int wave = tid >> 6, lane = tid & 63;
    for (int i = tid; i < 4096; i += 256) {
        WgL[0][i] = rd_elem(Wg1, i, isbf);
        WgL[1][i] = rd_elem(Wg2, i, isbf);
    }
    __syncthreads();

    for (int it = 0; it < 16; ++it) {
        int r = blockIdx.x * 64 + it * 4 + wave;
        int t = (r >> 12) * 8192 + 4096 + (r & 4095);
        float xr[8];
        if (isbf) {
            bf16x8 t8 = *(const bf16x8*)((const bf16_t*)xv + (size_t)t * 512 + lane * 8);
#pragma unroll
            for (int j = 0; j < 8; ++j) xr[j] = (float)t8[j];
        } else {
            const float* xp = (const float*)xv + (size_t)t * 512 + lane * 8;
            float4 u0 = *(const float4*)xp;
            float4 u1 = *(const float4*)(xp + 4);
            xr[0] = u0.x; xr[1] = u0.y; xr[2] = u0.z; xr[3] = u0.w;
            xr[4] = u1.x; xr[5] = u1.y; xr[6] = u1.z; xr[7] = u1.w;
        }
        float a[16];
#pragma unroll
        for (int e = 0; e < 16; ++e) a[e] = 0.0f;
#pragma unroll
        for (int j = 0; j < 8; ++j) {
            float xj = xr[j];
            int d = lane * 8 + j;
            const float* w1r = &WgL[0][d * 8];
            const float* w2r = &WgL[1][d * 8];
#pragma unroll
            for (int e = 0; e < 8; ++e) {
                a[e]     += xj * w1r[e];
                a[8 + e] += xj * w2r[e];
            }
        }
#pragma unroll
        for (int e = 0; e < 16; ++e) {
            a[e] += __shfl_xor(a[e], 32, 64);
            a[e] += __shfl_xor(a[e], 16, 64);
            a[e] += __shfl_xor(a[e], 8, 64);
            a[e] += __shfl_xor(a[e], 4, 64);
            a[e] += __shfl_xor(a[e], 2, 64);
            a[e] += __shfl_xor(a[e], 1, 64);
        }
        if (lane == 0) {
#pragma unroll
            for (int g = 0; g < 2; ++g) {
                float v0 = -1e30f, v1 = -1e30f;
                int i0 = 0, i1 = 0;
#pragma unroll
                for (int e = 0; e < 8; ++e) {
                    float vv = a[g * 8 + e];
                    if (vv > v0) { v0 = vv; i0 = e; }
                }
#pragma unroll
                for (int e = 0; e < 8; ++e) {
                    float vv = a[g * 8 + e];
                    if (e != i0 && vv > v1) { v1 = vv; i1 = e; }
                }
                float e1 = __expf(v1 - v0);
                float p0 = 1.0f / (1.0f + e1);
                float p1 = 1.0f - p0;
#pragma unroll
                for (int e = 0; e < 8; ++e)
                    wout[(size_t)r * 16 + g * 8 + e] =
                        (e == i0) ? p0 : ((e == i1) ? p1 : 0.0f);
            }
        }
    }
}

// ---------------------------------------------------------------------------
// GEMM: C = epilogue(A @ Bt^T), A/Bt bf16.
// R9: m201-style 8-phase 256x256 template in plain HIP.
//   BM=BN=256, BK=64, 512 thr = 8 waves (2M x 4N); wave owns 128x64 via
//   acc[8][4] of 16x16x32 MFMA. LDS 128 KB: As/Bs[2][256*64] double buffer.
//   Per K-tile: 4 phases; phase p = { ds_read A rows 2p,2p+1 (+ all B in
//   p0) ; issue 2 staged global_load_lds for tile t+1 ; s_barrier ;
//   setprio(1) ; 16 MFMA ; setprio(0) ; [counted vmcnt] ; s_barrier }.
//   Staging by 64-row bands, slot order p0:{A0,A2} p1:{B0,B1} p2:{B2,B3}
//   p3:{A1,A3}.  Waits derived from band deps (never 0 mid-loop):
//     p1: vmcnt(4)  gates this tile's A bands 1,3 (phases 2-3 reads)
//     p3: vmcnt(2)  gates next tile's phase-0/1 reads (A0,A2,B0-3 landed)
//   Last tile: p1 drains vmcnt(0), p3 wait skipped.
//   T2 swizzle (both sides, rule #21): 16B chunk ch of row holds global
//   k-chunk ch^(row&7); reads XOR with ln15&7 -> 2-way residual = free.
// EPI: 0 = +bias, store out (flag dtype)   [FFN2]
//      1 = gelu(+bias), bf16               [FFN1]
//      2 = gelu * wgt[grow*16+(col>>6)]    [MoE up]
//      3 = +=C masked (row&8191)>=id       [MoE down]
// ROWMAP: 0 identity(+off); 1 A-rows tokenmapped; 2 C-rows tokenmapped.
// Epilogue/rowmap index math identical to the R1 harness-verified 256² code.
// ---------------------------------------------------------------------------
#define PHASE_MFMA(RA, RB, A0_, A1_, A2_, A3_)                                \
    __builtin_amdgcn_s_setprio(1);                                            \
    _Pragma("unroll")                                                         \
    for (int c = 0; c < 4; ++c) {                                             \
        acc[RA][c] = __builtin_amdgcn_mfma_f32_16x16x32_bf16(A0_, bq[c][0], acc[RA][c], 0, 0, 0); \
        acc[RA][c] = __builtin_amdgcn_mfma_f32_16x16x32_bf16(A1_, bq[c][1], acc[RA][c], 0, 0, 0); \
        acc[RB][c] = __builtin_amdgcn_mfma_f32_16x16x32_bf16(A2_, bq[c][0], acc[RB][c], 0, 0, 0); \
        acc[RB][c] = __builtin_amdgcn_mfma_f32_16x16x32_bf16(A3_, bq[c][1], acc[RB][c], 0, 0, 0); \
    }                                                                         \
    __builtin_amdgcn_s_setprio(0);

template <int EPI, int ROWMAP>
__global__ __launch_bounds__(512, 2) void gemm_kernel(
    const bf16_t* __restrict__ A, int lda,
    const bf16_t* __restrict__ Bt, int ldb,
    void* __restrict__ Cv, int ldc, int K,
    int off1, int off2,
    const void* __restrict__ biasv,
    const float* __restrict__ wgt,
    const int* __restrict__ id_ptr,
    const int* __restrict__ flagp)
{
    __shared__ __align__(16) bf16_t As[2][256 * 64];   // 32 KB per buf
    __shared__ __align__(16) bf16_t Bs[2][256 * 64];   // total 128 KB

    const int isbf = *flagp;
    const int tid  = threadIdx.x;
    const int lane = tid & 63;
    const int wave = tid >> 6;              // 0..7
    const int wm = wave >> 2, wn = wave & 3;
    const int ln15 = lane & 15, lg = lane >> 4;
    const int xorl = ln15 & 7;              // = (fragment row) & 7

    const int r0 = blockIdx.x * 256;
    const int c0 = blockIdx.y * 256;
    int rA0, rC0, grow0;
    if (ROWMAP == 0) {
        rA0 = off1 + r0; rC0 = off2 + r0; grow0 = 0;
    } else if (ROWMAP == 1) {
        int g = off1 + r0;                  // 256-aligned, no 4096 crossing
        rA0 = (g >> 12) * 8192 + 4096 + (g & 4095);
        rC0 = r0; grow0 = g;
    } else {
        int g = off1 + r0;
        rA0 = r0; grow0 = 0;
        rC0 = (g >> 12) * 8192 + 4096 + (g & 4095);
    }

    // Stage one 64-row band (4096 x 16B chunks/matrix, 512/band; 1/thread).
    // LDS linear (rule #21): chunk cc=band*512+tid at byte cc*16, wave-
    // uniform base + lane*16. Global src k-chunk = (cc&7) ^ (row&7).
    auto stageA = [&](int kt, int nb, int band) {
        int cc = band * 512 + tid;
        int row = cc >> 3;
        int gc = (cc & 7) ^ (row & 7);
        gload_lds16(A + (size_t)(rA0 + row) * lda + (kt * 64 + gc * 8),
                    (char*)(&As[nb][0]) + (band * 512 + wave * 64) * 16);
    };
    auto stageB = [&](int kt, int nb, int band) {
        int cc = band * 512 + tid;
        int row = cc >> 3;
        int gc = (cc & 7) ^ (row & 7);
        gload_lds16(Bt + (size_t)(c0 + row) * ldb + (kt * 64 + gc * 8),
                    (char*)(&Bs[nb][0]) + (band * 512 + wave * 64) * 16);
    };
    // Fragment reads (swizzled): global k-chunk q=ks*4+lg at LDS chunk q^xorl.
    auto rdA = [&](int b, int r, int ks) -> bf16x8 {
        int row = wm * 128 + r * 16 + ln15;
        return *(const bf16x8*)(&As[b][row * 64 + ((((ks << 2) + lg) ^ xorl) * 8)]);
    };
    auto rdB = [&](int b, int c, int ks) -> bf16x8 {
        int row = wn * 64 + c * 16 + ln15;
        return *(const bf16x8*)(&Bs[b][row * 64 + ((((ks << 2) + lg) ^ xorl) * 8)]);
    };

    f32x4 acc[8][4];
#pragma unroll
    for (int r = 0; r < 8; ++r)
#pragma unroll
        for (int c = 0; c < 4; ++c)
            acc[r][c] = (f32x4){0.f, 0.f, 0.f, 0.f};

    const int nkt = K >> 6;                 // BK=64; K in {512,1024,2048}
    // Prologue: tile 0, slot order A0,A2,B0..B3,A1,A3 (A1,A3 newest).
    stageA(0, 0, 0); stageA(0, 0, 2);
    stageB(0, 0, 0); stageB(0, 0, 1); stageB(0, 0, 2); stageB(0, 0, 3);
    stageA(0, 0, 1); stageA(0, 0, 3);
    asm volatile("s_waitcnt vmcnt(2)" ::: "memory");   // A0,A2,B0-3 landed
    asm volatile("s_barrier" ::: "memory");

    bf16x8 bq[4][2];
    for (int kt = 0; kt < nkt; ++kt) {
        const int b = kt & 1, nb = b ^ 1;
        const bool more = (kt + 1 < nkt);

        // ---- phase 0: rows 0-1 (+ all B) ----
        {
            bf16x8 a0 = rdA(b, 0, 0), a1 = rdA(b, 0, 1);
            bf16x8 a2 = rdA(b, 1, 0), a3 = rdA(b, 1, 1);
#pragma unroll
            for (int c = 0; c < 4; ++c) {
                bq[c][0] = rdB(b, c, 0); bq[c][1] = rdB(b, c, 1);
            }
            if (more) { stageA(kt + 1, nb, 0); stageA(kt + 1, nb, 2); }
            asm volatile("s_barrier" ::: "memory");
            PHASE_MFMA(0, 1, a0, a1, a2, a3)
            asm volatile("s_barrier" ::: "memory");
        }
        // ---- phase 1: rows 2-3 ----
        {
            bf16x8 a0 = rdA(b, 2, 0), a1 = rdA(b, 2, 1);
            bf16x8 a2 = rdA(b, 3, 0), a3 = rdA(b, 3, 1);
            if (more) { stageB(kt + 1, nb, 0); stageB(kt + 1, nb, 1); }
            asm volatile("s_barrier" ::: "memory");
            PHASE_MFMA(2, 3, a0, a1, a2, a3)
            // gate this tile's A bands 1,3 (issued at prev tile p3)
            if (more) asm volatile("s_waitcnt vmcnt(4)" ::: "memory");
            else      asm volatile("s_waitcnt vmcnt(0)" ::: "memory");
            asm volatile("s_barrier" ::: "memory");
        }
        // ---- phase 2: rows 4-5 ----
        {
            bf16x8 a0 = rdA(b, 4, 0), a1 = rdA(b, 4, 1);
            bf16x8 a2 = rdA(b, 5, 0), a3 = rdA(b, 5, 1);
            if (more) { stageB(kt + 1, nb, 2); stageB(kt + 1, nb, 3); }
            asm volatile("s_barrier" ::: "memory");
            PHASE_MFMA(4, 5, a0, a1, a2, a3)
            asm volatile("s_barrier" ::: "memory");
        }
        // ---- phase 3: rows 6-7 ----
        {
            bf16x8 a0 = rdA(b, 6, 0), a1 = rdA(b, 6, 1);
            bf16x8 a2 = rdA(b, 7, 0), a3 = rdA(b, 7, 1);
            if (more) { stageA(kt + 1, nb, 1); stageA(kt + 1, nb, 3); }
            asm volatile("s_barrier" ::: "memory");
            PHASE_MFMA(6, 7, a0, a1, a2, a3)
            // gate next tile's phase-0/1 reads (its A0,A2,B0-3 landed)
            if (more) asm volatile("s_waitcnt vmcnt(2)" ::: "memory");
            asm volatile("s_barrier" ::: "memory");
        }
    }

    const int idv = (EPI == 3) ? id_ptr[0] : 0;
    bf16_t* Cb = (bf16_t*)Cv;
    float*  Cf = (float*)Cv;

#pragma unroll
    for (int r = 0; r < 8; ++r) {
#pragma unroll
        for (int v = 0; v < 4; ++v) {
            int lrow = wm * 128 + r * 16 + lg * 4 + v;   // tile-local row
            int crow = rC0 + lrow;
#pragma unroll
            for (int c = 0; c < 4; ++c) {
                int col = c0 + wn * 64 + c * 16 + ln15;
                float val = acc[r][c][v];
                size_t oidx = (size_t)crow * ldc + col;
                if (EPI == 0) {
                    if (biasv) val += rd_elem(biasv, col, isbf);
                    if (isbf) Cb[oidx] = (bf16_t)val; else Cf[oidx] = val;
                } else if (EPI == 1) {
                    if (biasv) val += rd_elem(biasv, col, isbf);
                    Cb[oidx] = (bf16_t)gelu_f(val);
                } else if (EPI == 2) {
                    val = gelu_f(val) * wgt[(size_t)(grow0 + lrow) * 16 + (col >> 6)];
                    Cb[oidx] = (bf16_t)val;
                } else {  // EPI == 3
                    if ((crow & 8191) >= idv) {
                        if (isbf) Cb[oidx] = (bf16_t)((float)Cb[oidx] + val);
                        else      Cf[oidx] = Cf[oidx] + val;
                    }
                }
            }
        }
    }
}

// ---------------------------------------------------------------------------
extern "C" void kernel_launch(void* const* d_in, const int* in_sizes, int n_in,
                              void* d_out, int out_size, void* d_ws, size_t ws_size,
                              hipStream_t stream)
{
    const void* x   = d_in[0];
    const int*  idp = (const int*)d_in[1];
    const void* W1  = d_in[2];
    const void* b1  = d_in[3];
    const void* W2  = d_in[4];
    const void* b2  = d_in[5];
    const void* Wg1 = d_in[6];
    const void* Wa1 = d_in[7];
    const void* Wb1 = d_in[8];
    const void* Wg2 = d_in[9];
    const void* Wa2 = d_in[10];
    const void* Wb2 = d_in[11];

    char* p = (char*)d_ws;
    bf16_t* W1t  = (bf16_t*)(p);                 // 2 MB
    bf16_t* W2t  = (bf16_t*)(p + 2097152);       // 2 MB
    bf16_t* Wat  = (bf16_t*)(p + 4194304);       // 1 MB
    bf16_t* Wbt  = (bf16_t*)(p + 5242880);       // 1 MB
    float*  wbuf = (float*) (p + 6291456);       // 1 MB
    int*    flagp= (int*)   (p + 7340032);       // 64 KB slot
    bf16_t* xb   = (bf16_t*)(p + 7405568);       // 32 MB bf16 x
    bf16_t* big  = (bf16_t*)(p + 40960000);      // h / moeh

    const size_t base = 40960000ull;
    size_t cap = (ws_size > base) ? ws_size - base : 0;
    int Mc = 32768;                               // FFN h chunk [Mc,2048] bf16
    while ((size_t)Mc * 4096ull > cap && Mc > 256) Mc >>= 1;
    int Mcm = 16384;                              // MoE h chunk [Mcm,1024] bf16
    while ((size_t)Mcm * 2048ull > cap && Mcm > 256) Mcm >>= 1;

    detect_kernel<<<1, 256, 0, stream>>>((const unsigned int*)x, flagp);
    convert_kernel<<<8192, 256, 0, stream>>>(x, flagp, xb);
    pack_kernel<<<12288, 256, 0, stream>>>(W1, W2, Wa1, Wa2, Wb1, Wb2, flagp,
                                           W1t, W2t, Wat, Wbt);
    gate_kernel<<<256, 256, 0, stream>>>(x, Wg1, Wg2, flagp, wbuf);

    // FFN, chunked over rows: out[m:m+Mc] = gelu(x@W1+b1)@W2 + b2
    for (int m = 0; m < 32768; m += Mc) {
        gemm_kernel<1, 0><<<dim3(Mc / 256, 8), 512, 0, stream>>>(
            xb, 512, W1t, 512, big, 2048, 512, m, 0,
            b1, nullptr, nullptr, flagp);
        gemm_kernel<0, 0><<<dim3(Mc / 256, 2), 512, 0, stream>>>(
            big, 2048, W2t, 2048, d_out, 512, 2048, 0, m,
            b2, nullptr, nullptr, flagp);
    }
    // MoE, chunked over masked rows: out[map(g)] += (gelu(x@Wa)*w)@Wb
    for (int m = 0; m < 16384; m += Mcm) {
        gemm_kernel<2, 1><<<dim3(Mcm / 256, 4), 512, 0, stream>>>(
            xb, 512, Wat, 512, big, 1024, 512, m, 0,
            nullptr, wbuf, nullptr, flagp);
        gemm_kernel<3, 2><<<dim3(Mcm / 256, 2), 512, 0, stream>>>(
            big, 1024, Wbt, 1024, d_out, 512, 1024, m, 0,
            nullptr, nullptr, idp, flagp);
    }
}

// Round 4
// 522.901 us; speedup vs baseline: 1.0557x; 1.0557x over previous
//
#include <hip/hip_runtime.h>
#include <hip/hip_bf16.h>

typedef __bf16 bf16_t;
typedef __bf16 bf16x8 __attribute__((ext_vector_type(8)));
typedef float f32x4 __attribute__((ext_vector_type(4)));

#define AS1 __attribute__((address_space(1)))
#define AS3 __attribute__((address_space(3)))

__device__ __forceinline__ void gload_lds16(const void* g, void* l) {
    __builtin_amdgcn_global_load_lds((const AS1 void*)g, (AS3 void*)l, 16, 0, 0);
}

__device__ __forceinline__ float gelu_f(float x) {
    // jax.nn.gelu default: tanh approximation
    float u = 0.7978845608028654f * (x + 0.044715f * x * x * x);
    float e = __expf(2.0f * u);
    float t = 1.0f - 2.0f / (e + 1.0f);   // tanh(u), safe at +-inf
    return 0.5f * x * (1.0f + t);
}

// ---------------------------------------------------------------------------
// Dtype detect (validated R4): low-16 exponent-field concentration test.
// flag: 1 = bf16-packed inputs, 0 = f32 inputs. (R4 evidence: f32.)
// ---------------------------------------------------------------------------
__global__ void detect_kernel(const unsigned int* __restrict__ xw,
                              int* __restrict__ flagp)
{
    __shared__ int cnt;
    int tid = threadIdx.x;
    if (tid == 0) cnt = 0;
    __syncthreads();
    unsigned int w = xw[tid];
    int le = (w >> 7) & 0xFF;
    int ok = (le >= 0x60 && le <= 0x88) ? 1 : 0;
    atomicAdd(&cnt, ok);
    __syncthreads();
    if (tid == 0) *flagp = (cnt >= 128) ? 1 : 0;
}

__device__ __forceinline__ float rd_elem(const void* p, size_t idx, int isbf) {
    return isbf ? (float)((const bf16_t*)p)[idx] : ((const float*)p)[idx];
}

// ---------------------------------------------------------------------------
// Convert x -> bf16 xb [32768*512]. One 8-elem chunk per thread.
// ---------------------------------------------------------------------------
__global__ __launch_bounds__(256) void convert_kernel(
    const void* __restrict__ x, const int* __restrict__ flagp,
    bf16_t* __restrict__ xb)
{
    const int isbf = *flagp;
    size_t i = (size_t)blockIdx.x * 256 + threadIdx.x;   // chunk id, 2097152 total
    if (isbf) {
        ((bf16x8*)xb)[i] = ((const bf16x8*)x)[i];
    } else {
        const float* s = (const float*)x + i * 8;
        float4 u0 = *(const float4*)s;
        float4 u1 = *(const float4*)(s + 4);
        bf16x8 v;
        v[0] = (bf16_t)u0.x; v[1] = (bf16_t)u0.y;
        v[2] = (bf16_t)u0.z; v[3] = (bf16_t)u0.w;
        v[4] = (bf16_t)u1.x; v[5] = (bf16_t)u1.y;
        v[6] = (bf16_t)u1.z; v[7] = (bf16_t)u1.w;
        ((bf16x8*)xb)[i] = v;
    }
}

// ---------------------------------------------------------------------------
// Weight pack -> bf16 B^T ([N,K] row-major) copies in workspace.
//  W1t [2048][512], W2t [512][2048], Wat [1024][512], Wbt [512][1024].
// ---------------------------------------------------------------------------
__global__ __launch_bounds__(256) void pack_kernel(
    const void* __restrict__ W1, const void* __restrict__ W2,
    const void* __restrict__ Wa1, const void* __restrict__ Wa2,
    const void* __restrict__ Wb1, const void* __restrict__ Wb2,
    const int* __restrict__ flagp,
    bf16_t* __restrict__ W1t, bf16_t* __restrict__ W2t,
    bf16_t* __restrict__ Wat, bf16_t* __restrict__ Wbt)
{
    const int isbf = *flagp;
    int i = blockIdx.x * 256 + threadIdx.x;
    if (i < 1048576) {                       // W1t[n][k] = W1[k][n], [512,2048]
        int n = i >> 9, k = i & 511;
        W1t[i] = (bf16_t)rd_elem(W1, (size_t)k * 2048 + n, isbf);
    } else if (i < 2097152) {                // W2t[n][k] = W2[k][n], [2048,512]
        int j = i - 1048576;
        int n = j >> 11, k = j & 2047;
        W2t[j] = (bf16_t)rd_elem(W2, (size_t)k * 512 + n, isbf);
    } else if (i < 2621440) {                // Wat[n][d] = Wa_g[e][d][h]
        int j = i - 2097152;
        int n = j >> 9, d = j & 511;
        const void* Wa = (n < 512) ? Wa1 : Wa2;
        int nn = n & 511, e = nn >> 6, hh = nn & 63;
        Wat[j] = (bf16_t)rd_elem(Wa, ((size_t)e * 512 + d) * 64 + hh, isbf);
    } else {                                 // Wbt[dout][k] = Wb_g[e][h][dout]
        int j = i - 2621440;
        int d = j >> 10, n = j & 1023;
        const void* Wb = (n < 512) ? Wb1 : Wb2;
        int nn = n & 511;
        Wbt[j] = (bf16_t)rd_elem(Wb, (size_t)nn * 512 + d, isbf);
    }
}

// ---------------------------------------------------------------------------
// Gate: masked token r in [0,16384), token = (r>>12)*8192 + 4096 + (r&4095).
// CRITICAL (R5/R6 post-mortem): logits MUST be computed from x at source
// precision (f32 path), NOT from bf16 xb — top-2 selection is discontinuous;
// bf16-rounded logits flip near-tied expert choices vs the reference.
// ---------------------------------------------------------------------------
__global__ __launch_bounds__(256) void gate_kernel(
    const void* __restrict__ xv,
    const void* __restrict__ Wg1, const void* __restrict__ Wg2,
    const int* __restrict__ flagp,
    float* __restrict__ wout)
{
    __shared__ float WgL[2][4096];   // [512][8] each, f32
    const int isbf = *flagp;
    const int tid = threadIdx.x;
    const int wave = tid >> 6, lane = tid & 63;
    for (int i = tid; i < 4096; i += 256) {
        WgL[0][i] = rd_elem(Wg1, i, isbf);
        WgL[1][i] = rd_elem(Wg2, i, isbf);
    }
    __syncthreads();

    for (int it = 0; it < 16; ++it) {
        int r = blockIdx.x * 64 + it * 4 + wave;
        int t = (r >> 12) * 8192 + 4096 + (r & 4095);
        float xr[8];
        if (isbf) {
            bf16x8 t8 = *(const bf16x8*)((const bf16_t*)xv + (size_t)t * 512 + lane * 8);
#pragma unroll
            for (int j = 0; j < 8; ++j) xr[j] = (float)t8[j];
        } else {
            const float* xp = (const float*)xv + (size_t)t * 512 + lane * 8;
            float4 u0 = *(const float4*)xp;
            float4 u1 = *(const float4*)(xp + 4);
            xr[0] = u0.x; xr[1] = u0.y; xr[2] = u0.z; xr[3] = u0.w;
            xr[4] = u1.x; xr[5] = u1.y; xr[6] = u1.z; xr[7] = u1.w;
        }
        float a[16];
#pragma unroll
        for (int e = 0; e < 16; ++e) a[e] = 0.0f;
#pragma unroll
        for (int j = 0; j < 8; ++j) {
            float xj = xr[j];
            int d = lane * 8 + j;
            const float* w1r = &WgL[0][d * 8];
            const float* w2r = &WgL[1][d * 8];
#pragma unroll
            for (int e = 0; e < 8; ++e) {
                a[e]     += xj * w1r[e];
                a[8 + e] += xj * w2r[e];
            }
        }
#pragma unroll
        for (int e = 0; e < 16; ++e) {
            a[e] += __shfl_xor(a[e], 32, 64);
            a[e] += __shfl_xor(a[e], 16, 64);
            a[e] += __shfl_xor(a[e], 8, 64);
            a[e] += __shfl_xor(a[e], 4, 64);
            a[e] += __shfl_xor(a[e], 2, 64);
            a[e] += __shfl_xor(a[e], 1, 64);
        }
        if (lane == 0) {
#pragma unroll
            for (int g = 0; g < 2; ++g) {
                float v0 = -1e30f, v1 = -1e30f;
                int i0 = 0, i1 = 0;
#pragma unroll
                for (int e = 0; e < 8; ++e) {
                    float vv = a[g * 8 + e];
                    if (vv > v0) { v0 = vv; i0 = e; }
                }
#pragma unroll
                for (int e = 0; e < 8; ++e) {
                    float vv = a[g * 8 + e];
                    if (e != i0 && vv > v1) { v1 = vv; i1 = e; }
                }
                float e1 = __expf(v1 - v0);
                float p0 = 1.0f / (1.0f + e1);
                float p1 = 1.0f - p0;
#pragma unroll
                for (int e = 0; e < 8; ++e)
                    wout[(size_t)r * 16 + g * 8 + e] =
                        (e == i0) ? p0 : ((e == i1) ? p1 : 0.0f);
            }
        }
    }
}

// ---------------------------------------------------------------------------
// GEMM: C = epilogue(A @ Bt^T), A/Bt bf16. R10 = the harness-verified R0
// kernel (152.8us FFN1; fastest of R0-R3) with EXACTLY ONE change:
//
//   T1 XCD-chunked block remap, col-tile-fastest within an XCD.
//   HW dispatches linear block id round-robin across the 8 XCDs (m09/m157).
//   Remap  wg = (orig%8)*(nwg/8) + orig/8   [bijective; all grids nwg%8==0]
//   then   bx = wg / gridDim.y (M-panel), by = wg % gridDim.y (N-tile).
//   Consecutive blocks on ONE XCD now share the same 128KB A-panel (16x
//   L2 reuse for FFN1) and B (<=2MB) stays L2-resident per XCD. R0's
//   x-fastest order re-streamed all of A per column-group (~512MB from L3
//   for FFN1) -> CUs starved at ~L3 feed; MfmaUtil 18%, VALUBusy 43%.
//
// Schedule deliberately unchanged from R0 (R2/R3 proved conflict-fix and
// counted-vmcnt/8-phase are null-to-negative at this structure).
// EPI: 0 = +bias, store out (flag dtype)   [FFN2]
//      1 = gelu(+bias), bf16               [FFN1]
//      2 = gelu * wgt[grow*16+(col>>6)]    [MoE up]
//      3 = +=C masked (row&8191)>=id       [MoE down]
// ROWMAP: 0 identity(+off); 1 A-rows tokenmapped; 2 C-rows tokenmapped.
// ---------------------------------------------------------------------------
template <int EPI, int ROWMAP>
__global__ __launch_bounds__(256, 2) void gemm_kernel(
    const bf16_t* __restrict__ A, int lda,
    const bf16_t* __restrict__ Bt, int ldb,
    void* __restrict__ Cv, int ldc, int K,
    int off1, int off2,
    const void* __restrict__ biasv,
    const float* __restrict__ wgt,
    const int* __restrict__ id_ptr,
    const int* __restrict__ flagp)
{
    __shared__ __align__(16) bf16_t As[128 * 32];  // 8 KB = 512 x 16B chunks
    __shared__ __align__(16) bf16_t Bs[128 * 32];

    const int isbf = *flagp;
    const int tid = threadIdx.x;
    const int lane = tid & 63;
    const int wave = tid >> 6;
    const int wm = wave >> 1, wn = wave & 1;
    const int ln15 = lane & 15, lg = lane >> 4;

    // --- T1 XCD-chunked remap (the only R10 change) ---
    const int gy = gridDim.y;
    const int nwg = gridDim.x * gy;
    const int orig = blockIdx.y * gridDim.x + blockIdx.x;  // HW linear order
    const int wg = (orig & 7) * (nwg >> 3) + (orig >> 3);  // XCD-contiguous
    const int bx = wg / gy;          // M row-panel (held across gy blocks)
    const int by = wg % gy;          // N col-tile, fastest within XCD

    const int r0 = bx * 128;
    const int c0 = by * 128;
    int rA0, rC0, grow0;
    if (ROWMAP == 0) {
        rA0 = off1 + r0; rC0 = off2 + r0; grow0 = 0;
    } else if (ROWMAP == 1) {
        int g = off1 + r0;
        rA0 = (g >> 12) * 8192 + 4096 + (g & 4095);
        rC0 = r0; grow0 = g;
    } else {
        int g = off1 + r0;
        rA0 = r0; grow0 = 0;
        rC0 = (g >> 12) * 8192 + 4096 + (g & 4095);
    }

    f32x4 acc[4][4];
#pragma unroll
    for (int r = 0; r < 4; ++r)
#pragma unroll
        for (int c = 0; c < 4; ++c)
            acc[r][c] = (f32x4){0.f, 0.f, 0.f, 0.f};

    const int nK = K >> 5;
    for (int kt = 0; kt < nK; ++kt) {
        const int k0 = kt * 32;
        // chunk c = i*256+tid: row c>>2, elems (c&3)*8..+7 -> LDS bytes c*16.
        // LDS dst: wave-uniform base (i*256+wave*64)*16; HW adds lane*16.
#pragma unroll
        for (int i = 0; i < 2; ++i) {
            int chunk = i * 256 + tid;
            int row = chunk >> 2;
            int col = (chunk & 3) * 8;
            gload_lds16(A + (size_t)(rA0 + row) * lda + (k0 + col),
                        (char*)As + (i * 256 + wave * 64) * 16);
            gload_lds16(Bt + (size_t)(c0 + row) * ldb + (k0 + col),
                        (char*)Bs + (i * 256 + wave * 64) * 16);
        }
        __builtin_amdgcn_s_waitcnt(0);
        __syncthreads();

        bf16x8 af[4], bfr[4];
#pragma unroll
        for (int r = 0; r < 4; ++r)
            af[r] = *(const bf16x8*)(As + ((wm * 64 + r * 16 + ln15) * 32 + lg * 8));
#pragma unroll
        for (int c = 0; c < 4; ++c)
            bfr[c] = *(const bf16x8*)(Bs + ((wn * 64 + c * 16 + ln15) * 32 + lg * 8));
#pragma unroll
        for (int r = 0; r < 4; ++r)
#pragma unroll
            for (int c = 0; c < 4; ++c)
                acc[r][c] = __builtin_amdgcn_mfma_f32_16x16x32_bf16(
                    af[r], bfr[c], acc[r][c], 0, 0, 0);
        __syncthreads();
    }

    const int idv = (EPI == 3) ? id_ptr[0] : 0;
    bf16_t* Cb = (bf16_t*)Cv;
    float*  Cf = (float*)Cv;

#pragma unroll
    for (int r = 0; r < 4; ++r) {
#pragma unroll
        for (int v = 0; v < 4; ++v) {
            int lrow = wm * 64 + r * 16 + lg * 4 + v;   // tile-local row
            int crow = rC0 + lrow;
#pragma unroll
            for (int c = 0; c < 4; ++c) {
                int col = c0 + wn * 64 + c * 16 + ln15;
                float val = acc[r][c][v];
                size_t oidx = (size_t)crow * ldc + col;
                if (EPI == 0) {
                    if (biasv) val += rd_elem(biasv, col, isbf);
                    if (isbf) Cb[oidx] = (bf16_t)val; else Cf[oidx] = val;
                } else if (EPI == 1) {
                    if (biasv) val += rd_elem(biasv, col, isbf);
                    Cb[oidx] = (bf16_t)gelu_f(val);
                } else if (EPI == 2) {
                    val = gelu_f(val) * wgt[(size_t)(grow0 + lrow) * 16 + (col >> 6)];
                    Cb[oidx] = (bf16_t)val;
                } else {  // EPI == 3
                    if ((crow & 8191) >= idv) {
                        if (isbf) Cb[oidx] = (bf16_t)((float)Cb[oidx] + val);
                        else      Cf[oidx] = Cf[oidx] + val;
                    }
                }
            }
        }
    }
}

// ---------------------------------------------------------------------------
extern "C" void kernel_launch(void* const* d_in, const int* in_sizes, int n_in,
                              void* d_out, int out_size, void* d_ws, size_t ws_size,
                              hipStream_t stream)
{
    const void* x   = d_in[0];
    const int*  idp = (const int*)d_in[1];
    const void* W1  = d_in[2];
    const void* b1  = d_in[3];
    const void* W2  = d_in[4];
    const void* b2  = d_in[5];
    const void* Wg1 = d_in[6];
    const void* Wa1 = d_in[7];
    const void* Wb1 = d_in[8];
    const void* Wg2 = d_in[9];
    const void* Wa2 = d_in[10];
    const void* Wb2 = d_in[11];

    char* p = (char*)d_ws;
    bf16_t* W1t  = (bf16_t*)(p);                 // 2 MB
    bf16_t* W2t  = (bf16_t*)(p + 2097152);       // 2 MB
    bf16_t* Wat  = (bf16_t*)(p + 4194304);       // 1 MB
    bf16_t* Wbt  = (bf16_t*)(p + 5242880);       // 1 MB
    float*  wbuf = (float*) (p + 6291456);       // 1 MB
    int*    flagp= (int*)   (p + 7340032);       // 64 KB slot
    bf16_t* xb   = (bf16_t*)(p + 7405568);       // 32 MB bf16 x
    bf16_t* big  = (bf16_t*)(p + 40960000);      // h / moeh

    const size_t base = 40960000ull;
    size_t cap = (ws_size > base) ? ws_size - base : 0;
    int Mc = 32768;                               // FFN h chunk [Mc,2048] bf16
    while ((size_t)Mc * 4096ull > cap && Mc > 128) Mc >>= 1;
    int Mcm = 16384;                              // MoE h chunk [Mcm,1024] bf16
    while ((size_t)Mcm * 2048ull > cap && Mcm > 128) Mcm >>= 1;

    detect_kernel<<<1, 256, 0, stream>>>((const unsigned int*)x, flagp);
    convert_kernel<<<8192, 256, 0, stream>>>(x, flagp, xb);
    pack_kernel<<<12288, 256, 0, stream>>>(W1, W2, Wa1, Wa2, Wb1, Wb2, flagp,
                                           W1t, W2t, Wat, Wbt);
    gate_kernel<<<256, 256, 0, stream>>>(x, Wg1, Wg2, flagp, wbuf);

    // FFN, chunked over rows: out[m:m+Mc] = gelu(x@W1+b1)@W2 + b2
    for (int m = 0; m < 32768; m += Mc) {
        gemm_kernel<1, 0><<<dim3(Mc / 128, 16), 256, 0, stream>>>(
            xb, 512, W1t, 512, big, 2048, 512, m, 0,
            b1, nullptr, nullptr, flagp);
        gemm_kernel<0, 0><<<dim3(Mc / 128, 4), 256, 0, stream>>>(
            big, 2048, W2t, 2048, d_out, 512, 2048, 0, m,
            b2, nullptr, nullptr, flagp);
    }
    // MoE, chunked over masked rows: out[map(g)] += (gelu(x@Wa)*w)@Wb
    for (int m = 0; m < 16384; m += Mcm) {
        gemm_kernel<2, 1><<<dim3(Mcm / 128, 8), 256, 0, stream>>>(
            xb, 512, Wat, 512, big, 1024, 512, m, 0,
            nullptr, wbuf, nullptr, flagp);
        gemm_kernel<3, 2><<<dim3(Mcm / 128, 4), 256, 0, stream>>>(
            big, 1024, Wbt, 1024, d_out, 512, 1024, m, 0,
            nullptr, nullptr, idp, flagp);
    }
}

// Round 6
// 507.300 us; speedup vs baseline: 1.0881x; 1.0308x over previous
//
#include <hip/hip_runtime.h>
#include <hip/hip_bf16.h>

typedef __bf16 bf16_t;
typedef __bf16 bf16x8 __attribute__((ext_vector_type(8)));
typedef float f32x4 __attribute__((ext_vector_type(4)));

#define AS1 __attribute__((address_space(1)))
#define AS3 __attribute__((address_space(3)))

__device__ __forceinline__ void gload_lds16(const void* g, void* l) {
    __builtin_amdgcn_global_load_lds((const AS1 void*)g, (AS3 void*)l, 16, 0, 0);
}

__device__ __forceinline__ float gelu_f(float x) {
    // jax.nn.gelu default: tanh approximation
    float u = 0.7978845608028654f * (x + 0.044715f * x * x * x);
    float e = __expf(2.0f * u);
    float t = 1.0f - 2.0f / (e + 1.0f);   // tanh(u), safe at +-inf
    return 0.5f * x * (1.0f + t);
}

// ---------------------------------------------------------------------------
// Dtype detect (validated R4): low-16 exponent-field concentration test.
// flag: 1 = bf16-packed inputs, 0 = f32 inputs. (R4 evidence: f32.)
// ---------------------------------------------------------------------------
__global__ void detect_kernel(const unsigned int* __restrict__ xw,
                              int* __restrict__ flagp)
{
    __shared__ int cnt;
    int tid = threadIdx.x;
    if (tid == 0) cnt = 0;
    __syncthreads();
    unsigned int w = xw[tid];
    int le = (w >> 7) & 0xFF;
    int ok = (le >= 0x60 && le <= 0x88) ? 1 : 0;
    atomicAdd(&cnt, ok);
    __syncthreads();
    if (tid == 0) *flagp = (cnt >= 128) ? 1 : 0;
}

__device__ __forceinline__ float rd_elem(const void* p, size_t idx, int isbf) {
    return isbf ? (float)((const bf16_t*)p)[idx] : ((const float*)p)[idx];
}

// ---------------------------------------------------------------------------
// Convert x -> bf16 xb [32768*512]. One 8-elem chunk per thread.
// ---------------------------------------------------------------------------
__global__ __launch_bounds__(256) void convert_kernel(
    const void* __restrict__ x, const int* __restrict__ flagp,
    bf16_t* __restrict__ xb)
{
    const int isbf = *flagp;
    size_t i = (size_t)blockIdx.x * 256 + threadIdx.x;   // chunk id, 2097152 total
    if (isbf) {
        ((bf16x8*)xb)[i] = ((const bf16x8*)x)[i];
    } else {
        const float* s = (const float*)x + i * 8;
        float4 u0 = *(const float4*)s;
        float4 u1 = *(const float4*)(s + 4);
        bf16x8 v;
        v[0] = (bf16_t)u0.x; v[1] = (bf16_t)u0.y;
        v[2] = (bf16_t)u0.z; v[3] = (bf16_t)u0.w;
        v[4] = (bf16_t)u1.x; v[5] = (bf16_t)u1.y;
        v[6] = (bf16_t)u1.z; v[7] = (bf16_t)u1.w;
        ((bf16x8*)xb)[i] = v;
    }
}

// ---------------------------------------------------------------------------
// Weight pack -> bf16 B^T ([N,K] row-major) copies in workspace.
//  W1t [2048][512], W2t [512][2048], Wat [1024][512], Wbt [512][1024].
// ---------------------------------------------------------------------------
__global__ __launch_bounds__(256) void pack_kernel(
    const void* __restrict__ W1, const void* __restrict__ W2,
    const void* __restrict__ Wa1, const void* __restrict__ Wa2,
    const void* __restrict__ Wb1, const void* __restrict__ Wb2,
    const int* __restrict__ flagp,
    bf16_t* __restrict__ W1t, bf16_t* __restrict__ W2t,
    bf16_t* __restrict__ Wat, bf16_t* __restrict__ Wbt)
{
    const int isbf = *flagp;
    int i = blockIdx.x * 256 + threadIdx.x;
    if (i < 1048576) {                       // W1t[n][k] = W1[k][n], [512,2048]
        int n = i >> 9, k = i & 511;
        W1t[i] = (bf16_t)rd_elem(W1, (size_t)k * 2048 + n, isbf);
    } else if (i < 2097152) {                // W2t[n][k] = W2[k][n], [2048,512]
        int j = i - 1048576;
        int n = j >> 11, k = j & 2047;
        W2t[j] = (bf16_t)rd_elem(W2, (size_t)k * 512 + n, isbf);
    } else if (i < 2621440) {                // Wat[n][d] = Wa_g[e][d][h]
        int j = i - 2097152;
        int n = j >> 9, d = j & 511;
        const void* Wa = (n < 512) ? Wa1 : Wa2;
        int nn = n & 511, e = nn >> 6, hh = nn & 63;
        Wat[j] = (bf16_t)rd_elem(Wa, ((size_t)e * 512 + d) * 64 + hh, isbf);
    } else {                                 // Wbt[dout][k] = Wb_g[e][h][dout]
        int j = i - 2621440;
        int d = j >> 10, n = j & 1023;
        const void* Wb = (n < 512) ? Wb1 : Wb2;
        int nn = n & 511;
        Wbt[j] = (bf16_t)rd_elem(Wb, (size_t)nn * 512 + d, isbf);
    }
}

// ---------------------------------------------------------------------------
// Gate: masked token r in [0,16384), token = (r>>12)*8192 + 4096 + (r&4095).
// CRITICAL (R5/R6 post-mortem): logits MUST be computed from x at source
// precision (f32 path), NOT from bf16 xb — top-2 selection is discontinuous;
// bf16-rounded logits flip near-tied expert choices vs the reference.
// ---------------------------------------------------------------------------
__global__ __launch_bounds__(256) void gate_kernel(
    const void* __restrict__ xv,
    const void* __restrict__ Wg1, const void* __restrict__ Wg2,
    const int* __restrict__ flagp,
    float* __restrict__ wout)
{
    __shared__ float WgL[2][4096];   // [512][8] each, f32
    const int isbf = *flagp;
    const int tid = threadIdx.x;
    const int wave = tid >> 6, lane = tid & 63;
    for (int i = tid; i < 4096; i += 256) {
        WgL[0][i] = rd_elem(Wg1, i, isbf);
        WgL[1][i] = rd_elem(Wg2, i, isbf);
    }
    __syncthreads();

    for (int it = 0; it < 16; ++it) {
        int r = blockIdx.x * 64 + it * 4 + wave;
        int t = (r >> 12) * 8192 + 4096 + (r & 4095);
        float xr[8];
        if (isbf) {
            bf16x8 t8 = *(const bf16x8*)((const bf16_t*)xv + (size_t)t * 512 + lane * 8);
#pragma unroll
            for (int j = 0; j < 8; ++j) xr[j] = (float)t8[j];
        } else {
            const float* xp = (const float*)xv + (size_t)t * 512 + lane * 8;
            float4 u0 = *(const float4*)xp;
            float4 u1 = *(const float4*)(xp + 4);
            xr[0] = u0.x; xr[1] = u0.y; xr[2] = u0.z; xr[3] = u0.w;
            xr[4] = u1.x; xr[5] = u1.y; xr[6] = u1.z; xr[7] = u1.w;
        }
        float a[16];
#pragma unroll
        for (int e = 0; e < 16; ++e) a[e] = 0.0f;
#pragma unroll
        for (int j = 0; j < 8; ++j) {
            float xj = xr[j];
            int d = lane * 8 + j;
            const float* w1r = &WgL[0][d * 8];
            const float* w2r = &WgL[1][d * 8];
#pragma unroll
            for (int e = 0; e < 8; ++e) {
                a[e]     += xj * w1r[e];
                a[8 + e] += xj * w2r[e];
            }
        }
#pragma unroll
        for (int e = 0; e < 16; ++e) {
            a[e] += __shfl_xor(a[e], 32, 64);
            a[e] += __shfl_xor(a[e], 16, 64);
            a[e] += __shfl_xor(a[e], 8, 64);
            a[e] += __shfl_xor(a[e], 4, 64);
            a[e] += __shfl_xor(a[e], 2, 64);
            a[e] += __shfl_xor(a[e], 1, 64);
        }
        if (lane == 0) {
#pragma unroll
            for (int g = 0; g < 2; ++g) {
                float v0 = -1e30f, v1 = -1e30f;
                int i0 = 0, i1 = 0;
#pragma unroll
                for (int e = 0; e < 8; ++e) {
                    float vv = a[g * 8 + e];
                    if (vv > v0) { v0 = vv; i0 = e; }
                }
#pragma unroll
                for (int e = 0; e < 8; ++e) {
                    float vv = a[g * 8 + e];
                    if (e != i0 && vv > v1) { v1 = vv; i1 = e; }
                }
                float e1 = __expf(v1 - v0);
                float p0 = 1.0f / (1.0f + e1);
                float p1 = 1.0f - p0;
#pragma unroll
                for (int e = 0; e < 8; ++e)
                    wout[(size_t)r * 16 + g * 8 + e] =
                        (e == i0) ? p0 : ((e == i1) ? p1 : 0.0f);
            }
        }
    }
}

// ---------------------------------------------------------------------------
// GEMM: C = epilogue(A @ Bt^T), A/Bt bf16. R12 = identical to R11/R5 source
// (bench infra failed; no data — resubmit). Structure: R4 base (T1 XCD
// remap, 128x128, 4 waves, acc[4][4]) + guide-verified minimum T3 2-phase
// recipe (m248v2): stage(t+1) FIRST, compute buf[t], ONE vmcnt(0)+s_barrier
// at end of iter. + T2 staging swizzle (R2-harness-verified conflict-free).
//
//   Single-barrier safety: every ds_read of buf[cur] feeds an MFMA issued
//   before the barrier, so its data has returned; staging into buf[cur]
//   next iter (after the barrier) cannot race those reads. Barrier count
//   uniform across waves (nK wave-uniform) — no divergent-barrier hang.
//
// EPI: 0 = +bias, store out (flag dtype)   [FFN2]
//      1 = gelu(+bias), bf16               [FFN1]
//      2 = gelu * wgt[grow*16+(col>>6)]    [MoE up]
//      3 = +=C masked (row&8191)>=id       [MoE down]
// ROWMAP: 0 identity(+off); 1 A-rows tokenmapped; 2 C-rows tokenmapped.
// ---------------------------------------------------------------------------
template <int EPI, int ROWMAP>
__global__ __launch_bounds__(256, 2) void gemm_kernel(
    const bf16_t* __restrict__ A, int lda,
    const bf16_t* __restrict__ Bt, int ldb,
    void* __restrict__ Cv, int ldc, int K,
    int off1, int off2,
    const void* __restrict__ biasv,
    const float* __restrict__ wgt,
    const int* __restrict__ id_ptr,
    const int* __restrict__ flagp)
{
    __shared__ __align__(16) bf16_t As[2][128 * 32];   // 8 KB per buf
    __shared__ __align__(16) bf16_t Bs[2][128 * 32];   // total 32 KB

    const int isbf = *flagp;
    const int tid = threadIdx.x;
    const int lane = tid & 63;
    const int wave = tid >> 6;
    const int wm = wave >> 1, wn = wave & 1;
    const int ln15 = lane & 15, lg = lane >> 4;
    const int rsw = (ln15 >> 1) & 3;        // ((fragment row)>>1)&3

    // --- T1 XCD-chunked remap (R4-verified: FETCH 131->49MB) ---
    const int gy = gridDim.y;
    const int nwg = gridDim.x * gy;
    const int orig = blockIdx.y * gridDim.x + blockIdx.x;  // HW linear order
    const int wg = (orig & 7) * (nwg >> 3) + (orig >> 3);  // XCD-contiguous
    const int bx = wg / gy;          // M row-panel (held across gy blocks)
    const int by = wg % gy;          // N col-tile, fastest within XCD

    const int r0 = bx * 128;
    const int c0 = by * 128;
    int rA0, rC0, grow0;
    if (ROWMAP == 0) {
        rA0 = off1 + r0; rC0 = off2 + r0; grow0 = 0;
    } else if (ROWMAP == 1) {
        int g = off1 + r0;
        rA0 = (g >> 12) * 8192 + 4096 + (g & 4095);
        rC0 = r0; grow0 = g;
    } else {
        int g = off1 + r0;
        rA0 = r0; grow0 = 0;
        rC0 = (g >> 12) * 8192 + 4096 + (g & 4095);
    }

    // Stage K-tile kt into buffer b. Chunk cc = i*256+tid lands at LDS byte
    // cc*16 (linear: wave-uniform base + lane*16, rule #21). Global source
    // k-chunk = (cc&3) ^ ((row>>1)&3)  [T2, R2-verified conflict-free].
    auto stage = [&](int kt, int b) {
        const int k0 = kt * 32;
#pragma unroll
        for (int i = 0; i < 2; ++i) {
            int cc = i * 256 + tid;
            int row = cc >> 2;
            int gc = (cc & 3) ^ ((row >> 1) & 3);
            gload_lds16(A + (size_t)(rA0 + row) * lda + (k0 + gc * 8),
                        (char*)(&As[b][0]) + (i * 256 + wave * 64) * 16);
            gload_lds16(Bt + (size_t)(c0 + row) * ldb + (k0 + gc * 8),
                        (char*)(&Bs[b][0]) + (i * 256 + wave * 64) * 16);
        }
    };

    f32x4 acc[4][4];
#pragma unroll
    for (int r = 0; r < 4; ++r)
#pragma unroll
        for (int c = 0; c < 4; ++c)
            acc[r][c] = (f32x4){0.f, 0.f, 0.f, 0.f};

    const int nK = K >> 5;                  // >= 16 for all our GEMMs
    stage(0, 0);
    asm volatile("s_waitcnt vmcnt(0)" ::: "memory");
    __builtin_amdgcn_s_barrier();

    for (int kt = 0; kt < nK; ++kt) {
        const int b = kt & 1;
        if (kt + 1 < nK) stage(kt + 1, b ^ 1);   // prefetch FIRST

        bf16x8 af[4], bfr[4];
#pragma unroll
        for (int r = 0; r < 4; ++r)
            af[r] = *(const bf16x8*)(
                &As[b][(wm * 64 + r * 16 + ln15) * 32 + ((lg ^ rsw) * 8)]);
#pragma unroll
        for (int c = 0; c < 4; ++c)
            bfr[c] = *(const bf16x8*)(
                &Bs[b][(wn * 64 + c * 16 + ln15) * 32 + ((lg ^ rsw) * 8)]);
#pragma unroll
        for (int r = 0; r < 4; ++r)
#pragma unroll
            for (int c = 0; c < 4; ++c)
                acc[r][c] = __builtin_amdgcn_mfma_f32_16x16x32_bf16(
                    af[r], bfr[c], acc[r][c], 0, 0, 0);

        if (kt + 1 < nK) {
            asm volatile("s_waitcnt vmcnt(0)" ::: "memory");  // t+1 landed
            __builtin_amdgcn_s_barrier();                     // one barrier
        }
    }

    const int idv = (EPI == 3) ? id_ptr[0] : 0;
    bf16_t* Cb = (bf16_t*)Cv;
    float*  Cf = (float*)Cv;

#pragma unroll
    for (int r = 0; r < 4; ++r) {
#pragma unroll
        for (int v = 0; v < 4; ++v) {
            int lrow = wm * 64 + r * 16 + lg * 4 + v;   // tile-local row
            int crow = rC0 + lrow;
#pragma unroll
            for (int c = 0; c < 4; ++c) {
                int col = c0 + wn * 64 + c * 16 + ln15;
                float val = acc[r][c][v];
                size_t oidx = (size_t)crow * ldc + col;
                if (EPI == 0) {
                    if (biasv) val += rd_elem(biasv, col, isbf);
                    if (isbf) Cb[oidx] = (bf16_t)val; else Cf[oidx] = val;
                } else if (EPI == 1) {
                    if (biasv) val += rd_elem(biasv, col, isbf);
                    Cb[oidx] = (bf16_t)gelu_f(val);
                } else if (EPI == 2) {
                    val = gelu_f(val) * wgt[(size_t)(grow0 + lrow) * 16 + (col >> 6)];
                    Cb[oidx] = (bf16_t)val;
                } else {  // EPI == 3
                    if ((crow & 8191) >= idv) {
                        if (isbf) Cb[oidx] = (bf16_t)((float)Cb[oidx] + val);
                        else      Cf[oidx] = Cf[oidx] + val;
                    }
                }
            }
        }
    }
}

// ---------------------------------------------------------------------------
extern "C" void kernel_launch(void* const* d_in, const int* in_sizes, int n_in,
                              void* d_out, int out_size, void* d_ws, size_t ws_size,
                              hipStream_t stream)
{
    const void* x   = d_in[0];
    const int*  idp = (const int*)d_in[1];
    const void* W1  = d_in[2];
    const void* b1  = d_in[3];
    const void* W2  = d_in[4];
    const void* b2  = d_in[5];
    const void* Wg1 = d_in[6];
    const void* Wa1 = d_in[7];
    const void* Wb1 = d_in[8];
    const void* Wg2 = d_in[9];
    const void* Wa2 = d_in[10];
    const void* Wb2 = d_in[11];

    char* p = (char*)d_ws;
    bf16_t* W1t  = (bf16_t*)(p);                 // 2 MB
    bf16_t* W2t  = (bf16_t*)(p + 2097152);       // 2 MB
    bf16_t* Wat  = (bf16_t*)(p + 4194304);       // 1 MB
    bf16_t* Wbt  = (bf16_t*)(p + 5242880);       // 1 MB
    float*  wbuf = (float*) (p + 6291456);       // 1 MB
    int*    flagp= (int*)   (p + 7340032);       // 64 KB slot
    bf16_t* xb   = (bf16_t*)(p + 7405568);       // 32 MB bf16 x
    bf16_t* big  = (bf16_t*)(p + 40960000);      // h / moeh

    const size_t base = 40960000ull;
    size_t cap = (ws_size > base) ? ws_size - base : 0;
    int Mc = 32768;                               // FFN h chunk [Mc,2048] bf16
    while ((size_t)Mc * 4096ull > cap && Mc > 128) Mc >>= 1;
    int Mcm = 16384;                              // MoE h chunk [Mcm,1024] bf16
    while ((size_t)Mcm * 2048ull > cap && Mcm > 128) Mcm >>= 1;

    detect_kernel<<<1, 256, 0, stream>>>((const unsigned int*)x, flagp);
    convert_kernel<<<8192, 256, 0, stream>>>(x, flagp, xb);
    pack_kernel<<<12288, 256, 0, stream>>>(W1, W2, Wa1, Wa2, Wb1, Wb2, flagp,
                                           W1t, W2t, Wat, Wbt);
    gate_kernel<<<256, 256, 0, stream>>>(x, Wg1, Wg2, flagp, wbuf);

    // FFN, chunked over rows: out[m:m+Mc] = gelu(x@W1+b1)@W2 + b2
    for (int m = 0; m < 32768; m += Mc) {
        gemm_kernel<1, 0><<<dim3(Mc / 128, 16), 256, 0, stream>>>(
            xb, 512, W1t, 512, big, 2048, 512, m, 0,
            b1, nullptr, nullptr, flagp);
        gemm_kernel<0, 0><<<dim3(Mc / 128, 4), 256, 0, stream>>>(
            big, 2048, W2t, 2048, d_out, 512, 2048, 0, m,
            b2, nullptr, nullptr, flagp);
    }
    // MoE, chunked over masked rows: out[map(g)] += (gelu(x@Wa)*w)@Wb
    for (int m = 0; m < 16384; m += Mcm) {
        gemm_kernel<2, 1><<<dim3(Mcm / 128, 8), 256, 0, stream>>>(
            xb, 512, Wat, 512, big, 1024, 512, m, 0,
            nullptr, wbuf, nullptr, flagp);
        gemm_kernel<3, 2><<<dim3(Mcm / 128, 4), 256, 0, stream>>>(
            big, 1024, Wbt, 1024, d_out, 512, 1024, m, 0,
            nullptr, nullptr, idp, flagp);
    }
}